// Round 1
// baseline (5247.028 us; speedup 1.0000x reference)
//
#include <hip/hip_runtime.h>

#define T_STEPS 256
#define BATCH   256
#define DIN     1024
#define DH      1024

typedef _Float16 half8_t __attribute__((ext_vector_type(8)));
typedef _Float16 half4_t __attribute__((ext_vector_type(4)));
typedef float    f32x4_t __attribute__((ext_vector_type(4)));

#define LDH  1032   // padded row stride (halves) for h-slab in LDS (bank spread)
#define REDS 36     // padded row stride (floats) for cross-wave reduce buffer

// ---------------------------------------------------------------------------
// Split W (1024 x 2048 fp32) into Wh = W[:, :1024] and Wx = W[:, 1024:], fp16.
// ---------------------------------------------------------------------------
__global__ __launch_bounds__(256) void cvt_w(const float* __restrict__ W,
                                             _Float16* __restrict__ Wh,
                                             _Float16* __restrict__ Wx) {
    const int part = blockIdx.x >> 9;                         // 0: Wh, 1: Wx
    size_t base = ((size_t)(blockIdx.x & 511) * 256 + threadIdx.x) * 8;
    const int n = (int)(base >> 10);
    const int k = (int)(base & 1023);
    const float4* s = reinterpret_cast<const float4*>(W + (size_t)n * 2048 + part * 1024 + k);
    float4 a = s[0], b = s[1];
    half8_t h;
    h[0] = (_Float16)a.x; h[1] = (_Float16)a.y;
    h[2] = (_Float16)a.z; h[3] = (_Float16)a.w;
    h[4] = (_Float16)b.x; h[5] = (_Float16)b.y;
    h[6] = (_Float16)b.z; h[7] = (_Float16)b.w;
    _Float16* dst = part ? Wx : Wh;
    *reinterpret_cast<half8_t*>(dst + base) = h;
}

// ---------------------------------------------------------------------------
// out[0] = h0 = zeros; block 0 also zeroes the sync flags (8 groups x 32 WGs,
// 16-int stride each).
// ---------------------------------------------------------------------------
__global__ __launch_bounds__(256) void zero_h0(float* __restrict__ out,
                                               int* __restrict__ flags) {
    size_t i = (size_t)blockIdx.x * 256 + threadIdx.x;
    reinterpret_cast<float4*>(out)[i] = make_float4(0.f, 0.f, 0.f, 0.f);
    if (blockIdx.x == 0) {
#pragma unroll
        for (int j = 0; j < 16; ++j) flags[(int)threadIdx.x * 16 + j] = 0;
    }
}

// ---------------------------------------------------------------------------
// Z = seq @ Wx^T + bias, written into out[1..256]. (unchanged)
// ---------------------------------------------------------------------------
__global__ __launch_bounds__(256) void zgemm(const float* __restrict__ seq,
                                             const _Float16* __restrict__ Wx,
                                             const float* __restrict__ bias,
                                             float* __restrict__ out) {
    __shared__ _Float16 la[64 * 136];
    __shared__ _Float16 lb[64 * 136];

    const int tid  = threadIdx.x;
    const int nblk = blockIdx.x;   // 0..15
    const int mblk = blockIdx.y;   // 0..1023

    const float* __restrict__ X = seq + (size_t)mblk * 64 * 1024;
    float* __restrict__ Z = out + (size_t)BATCH * DH + (size_t)mblk * 64 * 1024;

    const int ar = tid >> 2;
    const int ac = (tid & 3) * 32;
    const int br = tid >> 2;
    const int bc = (tid & 3) * 32;
    const _Float16* Bsrc = Wx + (size_t)(nblk * 64 + br) * 1024;

    float4 af[8];
    uint4  bp[4];

    auto load_tiles = [&](int kb) {
        const float4* s4 = reinterpret_cast<const float4*>(X + (size_t)ar * 1024 + kb + ac);
#pragma unroll
        for (int i = 0; i < 8; ++i) af[i] = s4[i];
        const uint4* sb = reinterpret_cast<const uint4*>(Bsrc + kb + bc);
#pragma unroll
        for (int i = 0; i < 4; ++i) bp[i] = sb[i];
    };
    auto store_tiles = [&]() {
#pragma unroll
        for (int i = 0; i < 4; ++i) {
            half8_t h;
            h[0] = (_Float16)af[2 * i].x; h[1] = (_Float16)af[2 * i].y;
            h[2] = (_Float16)af[2 * i].z; h[3] = (_Float16)af[2 * i].w;
            h[4] = (_Float16)af[2 * i + 1].x; h[5] = (_Float16)af[2 * i + 1].y;
            h[6] = (_Float16)af[2 * i + 1].z; h[7] = (_Float16)af[2 * i + 1].w;
            *reinterpret_cast<half8_t*>(&la[ar * 136 + ac + 8 * i]) = h;
        }
        uint4* d = reinterpret_cast<uint4*>(&lb[br * 136 + bc]);
#pragma unroll
        for (int i = 0; i < 4; ++i) d[i] = bp[i];
    };

    const int wave = tid >> 6;
    const int lane = tid & 63;
    const int fr   = lane & 15;
    const int quad = lane >> 4;
    const int wm   = (wave >> 1) * 32;
    const int wn   = (wave & 1) * 32;

    f32x4_t acc[2][2] = {{{0.f,0.f,0.f,0.f},{0.f,0.f,0.f,0.f}},
                         {{0.f,0.f,0.f,0.f},{0.f,0.f,0.f,0.f}}};

    load_tiles(0);
#pragma unroll 1
    for (int it = 0; it < 8; ++it) {
        store_tiles();
        __syncthreads();
        if (it < 7) load_tiles((it + 1) * 128);
        const _Float16* pa0 = &la[(wm + fr) * 136 + quad * 8];
        const _Float16* pa1 = &la[(wm + 16 + fr) * 136 + quad * 8];
        const _Float16* pb0 = &lb[(wn + fr) * 136 + quad * 8];
        const _Float16* pb1 = &lb[(wn + 16 + fr) * 136 + quad * 8];
#pragma unroll
        for (int kk = 0; kk < 4; ++kk) {
            half8_t a0 = *reinterpret_cast<const half8_t*>(pa0 + kk * 32);
            half8_t a1 = *reinterpret_cast<const half8_t*>(pa1 + kk * 32);
            half8_t b0 = *reinterpret_cast<const half8_t*>(pb0 + kk * 32);
            half8_t b1 = *reinterpret_cast<const half8_t*>(pb1 + kk * 32);
            acc[0][0] = __builtin_amdgcn_mfma_f32_16x16x32_f16(a0, b0, acc[0][0], 0, 0, 0);
            acc[0][1] = __builtin_amdgcn_mfma_f32_16x16x32_f16(a0, b1, acc[0][1], 0, 0, 0);
            acc[1][0] = __builtin_amdgcn_mfma_f32_16x16x32_f16(a1, b0, acc[1][0], 0, 0, 0);
            acc[1][1] = __builtin_amdgcn_mfma_f32_16x16x32_f16(a1, b1, acc[1][1], 0, 0, 0);
        }
        __syncthreads();
    }

    const float bv0 = bias[nblk * 64 + wn + fr];
    const float bv1 = bias[nblk * 64 + wn + 16 + fr];
#pragma unroll
    for (int i = 0; i < 2; ++i) {
        const int ml = wm + i * 16 + quad * 4;
#pragma unroll
        for (int r = 0; r < 4; ++r) {
            Z[(size_t)(ml + r) * 1024 + nblk * 64 + wn + fr]      = acc[i][0][r] + bv0;
            Z[(size_t)(ml + r) * 1024 + nblk * 64 + wn + 16 + fr] = acc[i][1][r] + bv1;
        }
    }
}

// ---------------------------------------------------------------------------
// Persistent recurrence: 256 WGs (1/CU), each owns a 32x32 tile of h.
//   group m = blockIdx.x & 7  (batch rows m*32..m*32+31) -> XCD-local
//   n       = blockIdx.x >> 3 (hidden cols n*32..n*32+31)
// Wh fragments held in registers (split-K: wave w owns k in [w*256, w*256+256)).
// Per step: wait on 32 peer flags -> stage fp16 h-slab to LDS via
// global_load_lds -> 32 MFMAs/wave -> LDS reduce of 4 partials -> fused
// Z-add + tanh -> write fp32 out + fp16 Hh[(t+1)&1] -> release own flag.
// ---------------------------------------------------------------------------
__global__ __launch_bounds__(256, 1) void rnn_persist(
        const _Float16* __restrict__ Wh,
        _Float16* __restrict__ Hh,
        int* __restrict__ flags,
        float* __restrict__ out) {
    __shared__ __align__(16) _Float16 hL[32 * LDH];
    __shared__ __align__(16) float red[4 * 32 * REDS];

    const int tid  = threadIdx.x;
    const int m    = blockIdx.x & 7;
    const int n    = blockIdx.x >> 3;
    const int wave = tid >> 6;
    const int lane = tid & 63;
    const int fr   = lane & 15;
    const int quad = lane >> 4;

    // Wh fragments for this wave's K-slice, resident in VGPRs for all steps.
    half8_t bfrag[8][2];
    {
        const _Float16* wp = Wh + (size_t)n * 32 * 1024 + wave * 256 + quad * 8;
#pragma unroll
        for (int ks = 0; ks < 8; ++ks)
#pragma unroll
            for (int ni = 0; ni < 2; ++ni)
                bfrag[ks][ni] = *reinterpret_cast<const half8_t*>(
                    wp + (size_t)(ni * 16 + fr) * 1024 + ks * 32);
    }

    const int orow = tid >> 3;          // 0..31
    const int ocol = (tid & 7) * 4;     // 0..28
    const size_t orowg = (size_t)(m * 32 + orow);
    int* myflag = flags + (m * 32 + n) * 16;

    // ---- t = 0: h1 = tanh(Z0) since h0 == 0 ----
    {
        float* o1 = out + ((size_t)1 * BATCH + orowg) * DH + n * 32 + ocol;
        float4 z = *reinterpret_cast<const float4*>(o1);
        float4 v = make_float4(tanhf(z.x), tanhf(z.y), tanhf(z.z), tanhf(z.w));
        *reinterpret_cast<float4*>(o1) = v;
        half4_t h;
        h[0] = (_Float16)v.x; h[1] = (_Float16)v.y;
        h[2] = (_Float16)v.z; h[3] = (_Float16)v.w;
        *reinterpret_cast<half4_t*>(
            Hh + ((size_t)1 * BATCH + orowg) * DH + n * 32 + ocol) = h;
        __syncthreads();
        if (tid == 0)
            __hip_atomic_store(myflag, 1, __ATOMIC_RELEASE, __HIP_MEMORY_SCOPE_AGENT);
    }

    for (int t = 1; t < T_STEPS; ++t) {
        // Z prefetch (own tile of out[t+1], written by zgemm; no other writer).
        float* ozp = out + ((size_t)(t + 1) * BATCH + orowg) * DH + n * 32 + ocol;
        float4 z = *reinterpret_cast<const float4*>(ozp);

        // Wait for all 32 producers of slab m to have completed step t-1.
        if (tid < 32) {
            const int* f = flags + (m * 32 + tid) * 16;
            int guard = 0;
            while (__hip_atomic_load(f, __ATOMIC_ACQUIRE, __HIP_MEMORY_SCOPE_AGENT) < t) {
                if (++guard > (1 << 22)) break;   // bailout -> visible wrongness, not hang
            }
        }
        __syncthreads();

        // Stage h_t slab (32 x 1024 fp16) into LDS. 64 chunks of 1024 B.
        const _Float16* hsrc = Hh + ((size_t)(t & 1) * BATCH + (size_t)m * 32) * DH;
#pragma unroll
        for (int i = 0; i < 16; ++i) {
            const int c   = wave * 16 + i;
            const int row = c >> 1;
            const int hf  = c & 1;
            const _Float16* src = hsrc + (size_t)row * DH + hf * 512 + lane * 8;
            __builtin_amdgcn_global_load_lds(
                (const __attribute__((address_space(1))) void*)src,
                (__attribute__((address_space(3))) void*)&hL[row * LDH + hf * 512],
                16, 0, 0);
        }
        __syncthreads();

        f32x4_t acc00 = {0.f,0.f,0.f,0.f}, acc01 = {0.f,0.f,0.f,0.f};
        f32x4_t acc10 = {0.f,0.f,0.f,0.f}, acc11 = {0.f,0.f,0.f,0.f};
        const int kb = wave * 256 + quad * 8;
#pragma unroll
        for (int ks = 0; ks < 8; ++ks) {
            half8_t a0 = *reinterpret_cast<const half8_t*>(&hL[fr * LDH + kb + ks * 32]);
            half8_t a1 = *reinterpret_cast<const half8_t*>(&hL[(16 + fr) * LDH + kb + ks * 32]);
            acc00 = __builtin_amdgcn_mfma_f32_16x16x32_f16(a0, bfrag[ks][0], acc00, 0, 0, 0);
            acc01 = __builtin_amdgcn_mfma_f32_16x16x32_f16(a0, bfrag[ks][1], acc01, 0, 0, 0);
            acc10 = __builtin_amdgcn_mfma_f32_16x16x32_f16(a1, bfrag[ks][0], acc10, 0, 0, 0);
            acc11 = __builtin_amdgcn_mfma_f32_16x16x32_f16(a1, bfrag[ks][1], acc11, 0, 0, 0);
        }

        // Cross-wave K-reduce via LDS.
        {
            float* rw = &red[wave * 32 * REDS];
#pragma unroll
            for (int r = 0; r < 4; ++r) {
                rw[(quad * 4 + r) * REDS + fr]           = acc00[r];
                rw[(quad * 4 + r) * REDS + 16 + fr]      = acc01[r];
                rw[(16 + quad * 4 + r) * REDS + fr]      = acc10[r];
                rw[(16 + quad * 4 + r) * REDS + 16 + fr] = acc11[r];
            }
        }
        __syncthreads();

        f32x4_t s = *reinterpret_cast<const f32x4_t*>(&red[orow * REDS + ocol]);
#pragma unroll
        for (int w = 1; w < 4; ++w) {
            f32x4_t p = *reinterpret_cast<const f32x4_t*>(
                &red[w * 32 * REDS + orow * REDS + ocol]);
            s[0] += p[0]; s[1] += p[1]; s[2] += p[2]; s[3] += p[3];
        }

        float4 v = make_float4(tanhf(s[0] + z.x), tanhf(s[1] + z.y),
                               tanhf(s[2] + z.z), tanhf(s[3] + z.w));
        *reinterpret_cast<float4*>(ozp) = v;
        half4_t h;
        h[0] = (_Float16)v.x; h[1] = (_Float16)v.y;
        h[2] = (_Float16)v.z; h[3] = (_Float16)v.w;
        *reinterpret_cast<half4_t*>(
            Hh + ((size_t)((t + 1) & 1) * BATCH + orowg) * DH + n * 32 + ocol) = h;

        __syncthreads();   // all threads' stores drained (vmcnt) before release
        if (tid == 0)
            __hip_atomic_store(myflag, t + 1, __ATOMIC_RELEASE, __HIP_MEMORY_SCOPE_AGENT);
    }
}

// ---------------------------------------------------------------------------
// Workspace layout (bytes):
//   [0, 2M)   Wh fp16 (1024 x 1024)
//   [2M, 4M)  Wx fp16 (1024 x 1024)
//   [4M, 5M)  Hh fp16 double buffer (2 x 256 x 1024)
//   [5M, +16K) flags int[8][32][16]
// ---------------------------------------------------------------------------
extern "C" void kernel_launch(void* const* d_in, const int* in_sizes, int n_in,
                              void* d_out, int out_size, void* d_ws, size_t ws_size,
                              hipStream_t stream) {
    const float* seq  = (const float*)d_in[0];   // (256, 256, 1024) fp32
    const float* W    = (const float*)d_in[1];   // (1024, 2048) fp32
    const float* bias = (const float*)d_in[2];   // (1024,) fp32
    float* out        = (float*)d_out;           // (257, 256, 1024) fp32
    _Float16* Wh      = (_Float16*)d_ws;
    _Float16* Wx      = (_Float16*)d_ws + 1024 * 1024;
    _Float16* Hh      = (_Float16*)d_ws + 2 * 1024 * 1024;
    int* flags        = (int*)((char*)d_ws + 5 * 1024 * 1024);

    hipLaunchKernelGGL(cvt_w, dim3(1024), dim3(256), 0, stream, W, Wh, Wx);
    hipLaunchKernelGGL(zero_h0, dim3(256), dim3(256), 0, stream, out, flags);
    hipLaunchKernelGGL(zgemm, dim3(16, 1024), dim3(256), 0, stream, seq, Wx, bias, out);
    hipLaunchKernelGGL(rnn_persist, dim3(256), dim3(256), 0, stream, Wh, Hh, flags, out);
}